// Round 1
// 89.491 us; speedup vs baseline: 1.0782x; 1.0782x over previous
//
#include <hip/hip_runtime.h>

#define OBJ_DIM 1024
#define NREL 8
#define NOBJ 4096
#define NPAIRS 65536

// ws layout (floats):
//   Wc   : [0, 16384)           -- REMAPPED combined weight: [16][1024],
//                                  q = h*8+r  (h=0: sub half, h=1: obj half)
//   cadd : [16384, 16392)       -- W2 @ b1 + b2  (full constant term)
//   pad  : [16392, 16400)
//   proj : [16400, 16400+65536) -- 4096 x 16: [q<8]=sub-proj(+cadd), [q>=8]=obj-proj
#define WC_OFF   0
#define CADD_OFF 16384
#define PROJ_OFF 16400

// NOTE (R4 post-mortem, kept): cooperative fusion of the three stages
// regressed 97 -> 161 us. grid.sync() on gfx950 costs ~25+ us each
// (device-scope fence + L2 writeback across 8 non-coherent XCDs);
// stream-ordered kernel boundaries are strictly cheaper. 3-kernel pipeline.
//
// NOTE (this round): profile shows the controllable cost is dispatch
// count/serialization, not BW (kernels are single-digit us vs ~53 us
// budget). So: memset node eliminated (prep is now atomic-free full-k),
// Wc stored pre-remapped so proj stages via global_load_lds, proj widened
// to 4 rows/wave (halves LDS dot + staging traffic), cvec+b2 folded into
// proj epilogue.

__device__ __forceinline__ void stage16(const void* g, void* l) {
    // async global->LDS DMA, 16B per lane; LDS dest = wave-uniform base + lane*16
    __builtin_amdgcn_global_load_lds(
        (const __attribute__((address_space(1))) void*)g,
        (__attribute__((address_space(3))) void*)l,
        16, 0, 0);
}

// ---------------------------------------------------------------------------
// Kernel A (prep): atomic-free, no zero-init needed.
// Blocks 0..255: block b owns 8 output columns c = b*8 .. b*8+8 and the FULL
// k=1024 contraction: Wc_remap[(h*8+r)*1024 + (c&1023)] = sum_k W2[r][k]*W1[k][c].
//   thread t: cq = t&1 (which float4 of the 8 cols), kg = t>>1 (k-slice of 8).
//   W1 reads: 32 rows x 32B per wave-instr (50% line use; L3 dedups HBM side).
//   In-block reduce via LDS stride-33 scratch: writes (t+j)%32 banks -> 2-way
//   (free); reads 2-way. One plain store per output, no atomics, no memset.
// Block 256: cadd[r] = sum_k W2[r][k]*b1[k] + b2[r].
// ---------------------------------------------------------------------------
__global__ __launch_bounds__(256) void prep_kernel(
    const float* __restrict__ W1, const float* __restrict__ W2,
    const float* __restrict__ b1, const float* __restrict__ b2,
    float* __restrict__ Wc, float* __restrict__ cadd)
{
    __shared__ float part[256 * 33];   // 33.8 KB scratch (both branches)

    const int t = threadIdx.x;
    const int b = blockIdx.x;

    if (b < 256) {
        const int cq = t & 1;          // float4 index within the 8 cols
        const int kg = t >> 1;         // 0..127, covers k = kg*8 .. kg*8+8
        const float4* W14 = (const float4*)W1;   // row stride 512 float4

        // preload this thread's W2 slice: [8 r][8 kk]
        float w2r[8][8];
#pragma unroll
        for (int r = 0; r < 8; ++r) {
            const float4* w2p = (const float4*)(W2 + r * 1024 + kg * 8);
            const float4 wa = w2p[0], wb = w2p[1];
            w2r[r][0] = wa.x; w2r[r][1] = wa.y; w2r[r][2] = wa.z; w2r[r][3] = wa.w;
            w2r[r][4] = wb.x; w2r[r][5] = wb.y; w2r[r][6] = wb.z; w2r[r][7] = wb.w;
        }

        float acc[8][4] = {};
#pragma unroll
        for (int kk = 0; kk < 8; ++kk) {
            const int k = kg * 8 + kk;
            const float4 w1 = W14[(size_t)k * 512 + b * 2 + cq];
#pragma unroll
            for (int r = 0; r < 8; ++r) {
                acc[r][0] += w2r[r][kk] * w1.x;
                acc[r][1] += w2r[r][kk] * w1.y;
                acc[r][2] += w2r[r][kk] * w1.z;
                acc[r][3] += w2r[r][kk] * w1.w;
            }
        }

        // partials: part[t*33 + j], j = r*4 + c  (banks (t+j)%32 -> 2-way, free)
#pragma unroll
        for (int r = 0; r < 8; ++r)
#pragma unroll
            for (int c = 0; c < 4; ++c)
                part[t * 33 + r * 4 + c] = acc[r][c];
        __syncthreads();

        // 64 outputs: o = t -> (r = t>>3, cc = t&7); sum over 128 kg slices
        if (t < 64) {
            const int r = t >> 3, cc = t & 7;
            const int cqo = cc >> 2, j = (r << 2) + (cc & 3);
            float s0 = 0.f, s1 = 0.f;
#pragma unroll 8
            for (int u = 0; u < 128; u += 2) {
                s0 += part[((u    ) * 2 + cqo) * 33 + j];
                s1 += part[((u + 1) * 2 + cqo) * 33 + j];
            }
            const int cglob = b * 8 + cc;              // 0..2047
            const int h = cglob >> 10, kcol = cglob & 1023;
            Wc[(h * 8 + r) * 1024 + kcol] = s0 + s1;
        }
    } else {
        // cadd block: k = 4t..4t+4 per thread, coalesced float4
        const float4 bv = ((const float4*)b1)[t];
        float acc[8];
#pragma unroll
        for (int r = 0; r < 8; ++r) {
            const float4 w = ((const float4*)(W2 + r * 1024))[t];
            acc[r] = w.x * bv.x + w.y * bv.y + w.z * bv.z + w.w * bv.w;
        }
#pragma unroll
        for (int r = 0; r < 8; ++r) part[t * 9 + r] = acc[r];   // 9 coprime 32
        __syncthreads();
        if (t < 64) {
            const int r = t & 7, g = t >> 3;    // t = g*8 + r
            float s = 0.f;
#pragma unroll 8
            for (int u = 0; u < 32; ++u) s += part[(g * 32 + u) * 9 + r];
            s += __shfl_down(s, 32);
            s += __shfl_down(s, 16);
            s += __shfl_down(s, 8);
            if (g == 0) cadd[r] = s + b2[r];
        }
    }
}

// ---------------------------------------------------------------------------
// Kernel B (proj): proj[n][q] = dot(obj[n], Wc[q]) (+cadd[q] for q<8).
// 256 blocks x 256 threads, 16 rows/block, 4 rows/wave.
//   Staging: Wc is already in [16][1024] layout -> pure linear 64 KB copy via
//   global_load_lds (no VGPR round-trip, no remap math).
//   Dot: per q: 4 ds_read_b128 shared by 4 rows -> per-CU LDS dot cycles
//   halve vs the 2-row version; obj loads stay perfectly coalesced (1 KB/instr).
//   Reduce: two passes of the proven stride-36 transpose (rows 0-1, rows 2-3),
//   reusing the 64 KB region as wave-private scratch after a barrier.
// ---------------------------------------------------------------------------
__global__ __launch_bounds__(256) void proj_kernel(
    const float* __restrict__ obj, const float* __restrict__ Wc,
    const float* __restrict__ cadd, float* __restrict__ proj)
{
    __shared__ float sh[16 * 1024];   // 64 KB: lWc during dot, scratch after

    const int t = threadIdx.x;
    const float4* Wc4 = (const float4*)Wc;
    float4* sh4 = (float4*)sh;
#pragma unroll
    for (int i = 0; i < 16; ++i)
        stage16(&Wc4[t + 256 * i], &sh4[t + 256 * i]);
    __syncthreads();   // drains vmcnt -> staging complete

    const int wave = t >> 6, lane = t & 63;
    const int n0 = blockIdx.x * 16 + wave * 4;
    const float4* xrow = (const float4*)(obj + (size_t)n0 * 1024);

    float4 x[4][4];
#pragma unroll
    for (int r = 0; r < 4; ++r)
#pragma unroll
        for (int i = 0; i < 4; ++i)
            x[r][i] = xrow[r * 256 + lane + 64 * i];   // 1 KB/instr, coalesced

    float a[4][16];
#pragma unroll
    for (int r = 0; r < 4; ++r)
#pragma unroll
        for (int q = 0; q < 16; ++q) a[r][q] = 0.f;

#pragma unroll
    for (int q = 0; q < 16; ++q) {
        const float4* wq = (const float4*)(sh + q * 1024);
#pragma unroll
        for (int i = 0; i < 4; ++i) {
            const float4 w = wq[lane + 64 * i];        // ds_read_b128
#pragma unroll
            for (int r = 0; r < 4; ++r)
                a[r][q] += w.x * x[r][i].x + w.y * x[r][i].y
                         + w.z * x[r][i].z + w.w * x[r][i].w;
        }
    }
    __syncthreads();   // everyone done reading lWc -> safe to reuse as scratch

    // wave-private scratch: scr[src_lane*36 + o], o = rowpair*16+q in [0,32)
    float* scr = sh + wave * 2304;           // 63*36+32 = 2300 floats needed
#pragma unroll
    for (int pass = 0; pass < 2; ++pass) {
        const int ra = pass * 2, rb = pass * 2 + 1;
#pragma unroll
        for (int q4 = 0; q4 < 16; q4 += 4) {
            *((float4*)&scr[lane * 36 + q4]) =
                make_float4(a[ra][q4], a[ra][q4 + 1], a[ra][q4 + 2], a[ra][q4 + 3]);
            *((float4*)&scr[lane * 36 + 16 + q4]) =
                make_float4(a[rb][q4], a[rb][q4 + 1], a[rb][q4 + 2], a[rb][q4 + 3]);
        }
        __syncthreads();   // order write->read (wave-private; barrier = safe)

        const int o = lane >> 1, half = lane & 1;
        float s = 0.f;
#pragma unroll 8
        for (int j = 0; j < 32; ++j)
            s += scr[(half * 32 + j) * 36 + o];   // banks (4j+o)%32: 2-way only
        s += __shfl_down(s, 1);
        if (half == 0) {
            const int row = o >> 4, q = o & 15;
            const float v = s + (q < 8 ? cadd[q] : 0.f);
            proj[(size_t)(n0 + ra + row) * 16 + q] = v;
        }
        __syncthreads();   // reads done before next pass overwrites scratch
    }
}

// ---------------------------------------------------------------------------
// Kernel C (gather): out[p][r] = proj[i][r] + proj[j][8+r]
// (constant term already folded into the sub half of proj).
// One thread per pair; proj table (256 KB) is L2-resident after kernel B.
// ---------------------------------------------------------------------------
__global__ __launch_bounds__(256) void gather_kernel(
    const int* __restrict__ pairs, const float* __restrict__ proj,
    float* __restrict__ out)
{
    const int p = blockIdx.x * 256 + threadIdx.x;

    const int2 ij = ((const int2*)pairs)[p];

    const float4* ps = (const float4*)(proj + (size_t)ij.x * 16);
    const float4* po = (const float4*)(proj + (size_t)ij.y * 16 + 8);
    const float4 s0 = ps[0], s1 = ps[1];
    const float4 o0 = po[0], o1 = po[1];

    float4 r0, r1;
    r0.x = s0.x + o0.x;  r0.y = s0.y + o0.y;
    r0.z = s0.z + o0.z;  r0.w = s0.w + o0.w;
    r1.x = s1.x + o1.x;  r1.y = s1.y + o1.y;
    r1.z = s1.z + o1.z;  r1.w = s1.w + o1.w;

    ((float4*)out)[(size_t)p * 2]     = r0;
    ((float4*)out)[(size_t)p * 2 + 1] = r1;
}

extern "C" void kernel_launch(void* const* d_in, const int* in_sizes, int n_in,
                              void* d_out, int out_size, void* d_ws, size_t ws_size,
                              hipStream_t stream) {
    const float* obj   = (const float*)d_in[0];   // 4096 x 1024
    const int*   pairs = (const int*)d_in[1];     // 65536 x 2 (int32 on device)
    const float* W1    = (const float*)d_in[2];   // 1024 x 2048
    const float* b1    = (const float*)d_in[3];   // 1024
    const float* W2    = (const float*)d_in[4];   // 8 x 1024
    const float* b2    = (const float*)d_in[5];   // 8
    float* out = (float*)d_out;

    float* ws   = (float*)d_ws;
    float* Wc   = ws + WC_OFF;
    float* cadd = ws + CADD_OFF;
    float* proj = ws + PROJ_OFF;

    // no memset: every ws word we read is written first this call
    // (Wc fully by prep blocks 0..255, cadd by block 256, proj by kernel B)

    prep_kernel<<<257, 256, 0, stream>>>(W1, W2, b1, b2, Wc, cadd);
    proj_kernel<<<256, 256, 0, stream>>>(obj, Wc, cadd, proj);
    gather_kernel<<<NPAIRS / 256, 256, 0, stream>>>(pairs, proj, out);
}